// Round 9
// baseline (1710.843 us; speedup 1.0000x reference)
//
#include <hip/hip_runtime.h>
#include <math.h>

#define N_ROWS 16384
#define M_ANCH 8192
#define DDIM   512
#define FDIM   2048
#define KNN    5
#define BN_EPS 1e-5f
#define CHUNK  8192    // encoder row chunk (h fp32 chunk = 64 MB, in score region)
#define SEED   1024    // dist seed chunk (approx scan sets threshold)
#define CAND_MAX 256   // per-row candidate buffer (E~55 with margin, overflow P ~ 0)
#define MARGIN 6.0f    // covers i8 key-error (sigma~0.66 per key, 6.4 sigma for pair)
#define QSCALE 28.0f   // i8 quant scale: clip at 127/28 = 4.54 sigma
#define TWO_INV_S2 (2.0f / (QSCALE * QSCALE))

typedef _Float16 f16;
typedef _Float16 f16x8 __attribute__((ext_vector_type(8)));
typedef _Float16 f16x4 __attribute__((ext_vector_type(4)));
typedef float f32x4 __attribute__((ext_vector_type(4)));
typedef int   i32x4 __attribute__((ext_vector_type(4)));

__device__ __forceinline__ void async_copy16(const void* g, void* l) {
    __builtin_amdgcn_global_load_lds(
        (const __attribute__((address_space(1))) void*)g,
        (__attribute__((address_space(3))) void*)l, 16, 0, 0);
}

__device__ __forceinline__ bool kless(float k1, int i1, float k2, int i2) {
    return (k1 < k2) || (k1 == k2 && i1 < i2);
}

__device__ __forceinline__ void insert5(float (&bk)[KNN], int (&bi)[KNN], float key, int id) {
    if (!kless(key, id, bk[4], bi[4])) return;
    bool c3 = kless(key, id, bk[3], bi[3]);
    bool c2 = kless(key, id, bk[2], bi[2]);
    bool c1 = kless(key, id, bk[1], bi[1]);
    bool c0 = kless(key, id, bk[0], bi[0]);
    bk[4] = c3 ? bk[3] : key;                  bi[4] = c3 ? bi[3] : id;
    bk[3] = c3 ? (c2 ? bk[2] : key) : bk[3];   bi[3] = c3 ? (c2 ? bi[2] : id) : bi[3];
    bk[2] = c2 ? (c1 ? bk[1] : key) : bk[2];   bi[2] = c2 ? (c1 ? bi[1] : id) : bi[2];
    bk[1] = c1 ? (c0 ? bk[0] : key) : bk[1];   bi[1] = c1 ? (c0 ? bi[0] : id) : bi[1];
    bk[0] = c0 ? key : bk[0];                  bi[0] = c0 ? id : bi[0];
}

__global__ void zero_kernel(float* p, int n) {
    int i = blockIdx.x * blockDim.x + threadIdx.x;
    if (i < n) p[i] = 0.f;
}

// fp32 -> i8 quant (round-nearest, clamp +-127), 4 elems -> packed u32.
__global__ __launch_bounds__(256) void quant_i8_kernel(const float* __restrict__ X,
                                                       unsigned int* __restrict__ Y, int n4) {
    int i = blockIdx.x * 256 + threadIdx.x;
    if (i >= n4) return;
    float4 v = ((const float4*)X)[i];
    int a = (int)rintf(v.x * QSCALE); a = a > 127 ? 127 : (a < -127 ? -127 : a);
    int b = (int)rintf(v.y * QSCALE); b = b > 127 ? 127 : (b < -127 ? -127 : b);
    int c = (int)rintf(v.z * QSCALE); c = c > 127 ? 127 : (c < -127 ? -127 : c);
    int d = (int)rintf(v.w * QSCALE); d = d > 127 ? 127 : (d < -127 ? -127 : d);
    Y[i] = (unsigned int)(a & 255) | ((unsigned int)(b & 255) << 8)
         | ((unsigned int)(c & 255) << 16) | ((unsigned int)(d & 255) << 24);
}

// fp32 [M,K] -> f16 [M, hi(K)|lo(K)] row-split (same formula as wsplit / the
// old in-GEMM split: hh=(f16)x; lo=(f16)(x-hh)) -> values bit-identical.
// LOG_K4 = log2(K/4).
__global__ __launch_bounds__(256) void rowsplit_kernel(const float* __restrict__ X,
                                                       f16* __restrict__ Y,
                                                       int n4, int log_k4) {
    int i4 = blockIdx.x * 256 + threadIdx.x;
    if (i4 >= n4) return;
    int K4 = 1 << log_k4;
    int row = i4 >> log_k4;
    int kc = (i4 & (K4 - 1)) * 4;
    float4 v = ((const float4*)X)[i4];
    f16x4 h, lo;
    h.x = (f16)v.x; h.y = (f16)v.y; h.z = (f16)v.z; h.w = (f16)v.w;
    lo.x = (f16)(v.x - (float)h.x); lo.y = (f16)(v.y - (float)h.y);
    lo.z = (f16)(v.z - (float)h.z); lo.w = (f16)(v.w - (float)h.w);
    f16* base = Y + (size_t)row * (K4 * 8) + kc;
    *(f16x4*)base = h;
    *(f16x4*)(base + K4 * 4) = lo;
}

__global__ __launch_bounds__(256) void anchor_norm_kernel(const float* __restrict__ a,
                                                          float* __restrict__ norm_a) {
    int wave = threadIdx.x >> 6, lane = threadIdx.x & 63;
    int row = blockIdx.x * 4 + wave;
    const float4* ar = (const float4*)(a + (size_t)row * DDIM);
    float4 v1 = ar[lane * 2];
    float4 v2 = ar[lane * 2 + 1];
    float s = v1.x*v1.x + v1.y*v1.y + v1.z*v1.z + v1.w*v1.w
            + v2.x*v2.x + v2.y*v2.y + v2.z*v2.z + v2.w*v2.w;
    for (int off = 32; off; off >>= 1) s += __shfl_xor(s, off, 64);
    if (lane == 0) norm_a[row] = s;
}

// i8 dist GEMM, double-buffered LDS (one barrier/K-step; next tile's
// global_load_lds issued before compute so L2 latency hides).
// COLLECT==0: writes key = norm[n] - 2*dot/S^2 to C (seed scan input).
// COLLECT==1: appends (id, exact norm) with key < thr[row] to candidate lists.
template<int COLLECT>
__global__ __launch_bounds__(256) void gemm_i8(
    const char* __restrict__ A, const char* __restrict__ B,
    const float* __restrict__ norm, const float* __restrict__ thr,
    int* __restrict__ cnt, int* __restrict__ cand_i, float* __restrict__ cand_n,
    int idofs, float* __restrict__ C, int Ncols)
{
    __shared__ char As[2][128 * 64];
    __shared__ char Bs[2][128 * 64];
    const int t = threadIdx.x;
    const int w = t >> 6, l = t & 63;
    const int m0 = blockIdx.y * 128, n0 = blockIdx.x * 128;
    const int wm = (w & 1) * 64, wn = (w >> 1) * 64;

    i32x4 acc[4][4];
    #pragma unroll
    for (int i = 0; i < 4; ++i)
        #pragma unroll
        for (int j = 0; j < 4; ++j) acc[i][j] = (i32x4){0, 0, 0, 0};

    const int srow = l >> 2;
    const int gq = ((l & 3) - (srow >> 1)) & 3;
    const int skoff = gq * 16;
    const int sqf = (((l >> 4) + (((l & 15) >> 1) & 3)) & 3) * 16;

    auto STAGE = [&](int buf, int kt) {
        int k0 = kt * 64;
        #pragma unroll
        for (int s = 0; s < 2; ++s) {
            int grp = w * 2 + s;
            int row = grp * 16 + srow;
            async_copy16(A + (size_t)(m0 + row) * DDIM + k0 + skoff,
                         &As[buf][grp * 1024 + l * 16]);
            async_copy16(B + (size_t)(n0 + row) * DDIM + k0 + skoff,
                         &Bs[buf][grp * 1024 + l * 16]);
        }
    };

    STAGE(0, 0);
    __syncthreads();

    for (int kt = 0; kt < 8; ++kt) {
        int cur = kt & 1;
        if (kt < 7) STAGE(cur ^ 1, kt + 1);
        i32x4 af[4], bf[4];
        #pragma unroll
        for (int i = 0; i < 4; ++i)
            af[i] = *(const i32x4*)&As[cur][(wm + i * 16 + (l & 15)) * 64 + sqf];
        #pragma unroll
        for (int j = 0; j < 4; ++j)
            bf[j] = *(const i32x4*)&Bs[cur][(wn + j * 16 + (l & 15)) * 64 + sqf];
        #pragma unroll
        for (int i = 0; i < 4; ++i)
            #pragma unroll
            for (int j = 0; j < 4; ++j)
                acc[i][j] = __builtin_amdgcn_mfma_i32_16x16x64_i8(af[i], bf[j], acc[i][j], 0, 0, 0);
        __syncthreads();
    }

    float nj[4];
    #pragma unroll
    for (int j = 0; j < 4; ++j) nj[j] = norm[n0 + wn + j * 16 + (l & 15)];

    if (COLLECT) {
        float thr4[4][4];
        #pragma unroll
        for (int i = 0; i < 4; ++i) {
            float4 tv = *(const float4*)&thr[m0 + wm + i * 16 + (l >> 4) * 4];
            thr4[i][0] = tv.x; thr4[i][1] = tv.y; thr4[i][2] = tv.z; thr4[i][3] = tv.w;
        }
        #pragma unroll
        for (int i = 0; i < 4; ++i)
            #pragma unroll
            for (int j = 0; j < 4; ++j)
                #pragma unroll
                for (int r = 0; r < 4; ++r) {
                    float key = nj[j] - TWO_INV_S2 * (float)acc[i][j][r];
                    if (key < thr4[i][r]) {
                        int row = m0 + wm + i * 16 + (l >> 4) * 4 + r;
                        int pos = atomicAdd(&cnt[row], 1);
                        if (pos < CAND_MAX) {
                            cand_i[(size_t)row * CAND_MAX + pos] =
                                idofs + n0 + wn + j * 16 + (l & 15);
                            cand_n[(size_t)row * CAND_MAX + pos] = nj[j];
                        }
                    }
                }
    } else {
        #pragma unroll
        for (int i = 0; i < 4; ++i)
            #pragma unroll
            for (int j = 0; j < 4; ++j)
                #pragma unroll
                for (int r = 0; r < 4; ++r) {
                    int m = m0 + wm + i * 16 + (l >> 4) * 4 + r;
                    int n = n0 + wn + j * 16 + (l & 15);
                    C[(size_t)m * Ncols + n] = nj[j] - TWO_INV_S2 * (float)acc[i][j][r];
                }
    }
}

// approx top-5 over seed keys -> thrbuf = 5th-best + MARGIN; appends all seed
// (id, exact norm) with key < thr to the candidate list (includes the top-5).
__global__ __launch_bounds__(256) void topk_scan_kernel(
    const float* __restrict__ g, const float* __restrict__ norm_a,
    float* __restrict__ thrbuf, int* __restrict__ cnt,
    int* __restrict__ cand_i, float* __restrict__ cand_n)
{
    int row = blockIdx.x * 4 + (threadIdx.x >> 6);
    int lane = threadIdx.x & 63;
    const float* grow = g + (size_t)row * SEED;
    float4 v0 = *(const float4*)(grow + lane * 4);
    float4 v1 = *(const float4*)(grow + 256 + lane * 4);
    float4 v2 = *(const float4*)(grow + 512 + lane * 4);
    float4 v3 = *(const float4*)(grow + 768 + lane * 4);
    float bk[KNN]; int bi[KNN];
    #pragma unroll
    for (int q = 0; q < KNN; ++q) { bk[q] = 3.0e38f; bi[q] = 0x7fffffff; }
    int c = lane * 4;
    insert5(bk, bi, v0.x, c);       insert5(bk, bi, v0.y, c + 1);
    insert5(bk, bi, v0.z, c + 2);   insert5(bk, bi, v0.w, c + 3);
    insert5(bk, bi, v1.x, c + 256); insert5(bk, bi, v1.y, c + 257);
    insert5(bk, bi, v1.z, c + 258); insert5(bk, bi, v1.w, c + 259);
    insert5(bk, bi, v2.x, c + 512); insert5(bk, bi, v2.y, c + 513);
    insert5(bk, bi, v2.z, c + 514); insert5(bk, bi, v2.w, c + 515);
    insert5(bk, bi, v3.x, c + 768); insert5(bk, bi, v3.y, c + 769);
    insert5(bk, bi, v3.z, c + 770); insert5(bk, bi, v3.w, c + 771);
    for (int off = 32; off >= 1; off >>= 1) {
        float ok[KNN]; int oi[KNN];
        #pragma unroll
        for (int q = 0; q < KNN; ++q) {
            ok[q] = __shfl_xor(bk[q], off, 64);
            oi[q] = __shfl_xor(bi[q], off, 64);
        }
        #pragma unroll
        for (int q = 0; q < KNN; ++q) insert5(bk, bi, ok[q], oi[q]);
    }
    float thr = bk[4] + MARGIN;
    if (lane == 0) thrbuf[row] = thr;
    int* rci = cand_i + (size_t)row * CAND_MAX;
    float* rcn = cand_n + (size_t)row * CAND_MAX;
    #define PUSH(v, id) if ((v) < thr) { int pos = atomicAdd(&cnt[row], 1); \
                                         if (pos < CAND_MAX) { rci[pos] = (id); \
                                         rcn[pos] = norm_a[(id)]; } }
    PUSH(v0.x, c)       PUSH(v0.y, c + 1)   PUSH(v0.z, c + 2)   PUSH(v0.w, c + 3)
    PUSH(v1.x, c + 256) PUSH(v1.y, c + 257) PUSH(v1.z, c + 258) PUSH(v1.w, c + 259)
    PUSH(v2.x, c + 512) PUSH(v2.y, c + 513) PUSH(v2.z, c + 514) PUSH(v2.w, c + 515)
    PUSH(v3.x, c + 768) PUSH(v3.y, c + 769) PUSH(v3.z, c + 770) PUSH(v3.w, c + 771)
    #undef PUSH
}

// exact fp32 rescore + fused gather/mean.  One wave per row (R6 control flow,
// measured 247us) + R8's conflict-free swizzled PREF (measured 0 conflicts):
// global floats [8l,8l+4) -> LDS slot l, [8l+4,8l+8) -> slot 64+l, so the
// ds_read_b128s are lane-stride-16B.  Lane l holds elements [8l,8l+8) ->
// dot/butterfly/insert bit-identical to the verified serial tree.
__global__ __launch_bounds__(256) void rescore_kernel(
    const float* __restrict__ src, const float* __restrict__ anchor,
    const int* __restrict__ cnt, const int* __restrict__ cand_i,
    const float* __restrict__ cand_n, float* __restrict__ neigh)
{
    __shared__ float lb[4][2][DDIM];   // [wave][dbuf][elem] = 16 KB
    int wv = threadIdx.x >> 6, lane = threadIdx.x & 63;
    int row = blockIdx.x * 4 + wv;
    const float4* sp = (const float4*)(src + (size_t)row * DDIM);
    float4 s0 = sp[lane * 2], s1 = sp[lane * 2 + 1];
    int c = cnt[row]; if (c > CAND_MAX) c = CAND_MAX;   // c >= 5 always
    const int* ci = cand_i + (size_t)row * CAND_MAX;
    const float* cn = cand_n + (size_t)row * CAND_MAX;

    float bk[KNN]; int bi[KNN];
    #pragma unroll
    for (int q = 0; q < KNN; ++q) { bk[q] = 3.0e38f; bi[q] = 0x7fffffff; }

    auto PREF = [&](int buf, int id) {
        const float* gp = anchor + (size_t)id * DDIM;
        async_copy16(gp + lane * 8,     &lb[wv][buf][lane * 4]);
        async_copy16(gp + lane * 8 + 4, &lb[wv][buf][256 + lane * 4]);
    };

    int   id_c = ci[0];          float n_c = cn[0];
    int   id_n = ci[1];          float n_n = cn[1];
    PREF(0, id_c);
    PREF(1, id_n);

    for (int p = 0; p < c; ++p) {
        int id_f = 0; float n_f = 0.f;
        if (p + 2 < c) { id_f = ci[p + 2]; n_f = cn[p + 2]; }
        // all VMEM older than {this iter's 2 scalar loads + prev iter's
        // PREF pair} has landed -> buffer for candidate p is ready.
        asm volatile("s_waitcnt vmcnt(4)" ::: "memory");
        const float* bc = &lb[wv][p & 1][0];
        float4 a0 = *(const float4*)&bc[lane * 4];        // elems [8l, 8l+4)
        float4 a1 = *(const float4*)&bc[256 + lane * 4];  // elems [8l+4, 8l+8)
        float d = s0.x*a0.x + s0.y*a0.y + s0.z*a0.z + s0.w*a0.w
                + s1.x*a1.x + s1.y*a1.y + s1.z*a1.z + s1.w*a1.w;
        #pragma unroll
        for (int off = 32; off; off >>= 1) d += __shfl_xor(d, off, 64);
        insert5(bk, bi, n_c - 2.f * d, id_c);
        if (p + 2 < c) PREF(p & 1, id_f);   // reuse just-consumed buffer
        id_c = id_n; n_c = n_n;
        id_n = id_f; n_n = n_f;
    }

    // fused gather + mean (top-5 anchor rows are cache-hot)
    const float4* a0 = (const float4*)(anchor + (size_t)bi[0] * DDIM);
    const float4* a1 = (const float4*)(anchor + (size_t)bi[1] * DDIM);
    const float4* a2 = (const float4*)(anchor + (size_t)bi[2] * DDIM);
    const float4* a3 = (const float4*)(anchor + (size_t)bi[3] * DDIM);
    const float4* a4 = (const float4*)(anchor + (size_t)bi[4] * DDIM);
    float4* np = (float4*)(neigh + (size_t)row * DDIM);
    #pragma unroll
    for (int p = 0; p < 2; ++p) {
        int c4 = lane + 64 * p;
        float4 v0 = a0[c4], v1 = a1[c4], v2 = a2[c4], v3 = a3[c4], v4 = a4[c4];
        float4 o;
        o.x = (v0.x + v1.x + v2.x + v3.x + v4.x) * 0.2f;
        o.y = (v0.y + v1.y + v2.y + v3.y + v4.y) * 0.2f;
        o.z = (v0.z + v1.z + v2.z + v3.z + v4.z) * 0.2f;
        o.w = (v0.w + v1.w + v2.w + v3.w + v4.w) * 0.2f;
        np[c4] = o;
    }
}

// Network GEMM v3: C = act(Asplit @ BwT + bias [+ C0]).  A pre-split by
// rowsplit_kernel to f16 [M, hi(K)|lo(K)] (identical split formula ->
// bit-identical values); both A and B staged by pure async global_load_lds
// into double-buffered LDS -- a direct clone of the verified gemm_i8
// pipeline (one barrier per K-step).  3-term MFMA order unchanged.
template<int ADDC0, int TANH, int K>
__global__ __launch_bounds__(256) void gemm_f16hl(
    const f16* __restrict__ Aw, const f16* __restrict__ Bw,
    const float* __restrict__ bias, const float* __restrict__ C0,
    float* __restrict__ C, int Ncols)
{
    __shared__ f16 Ah[2][128 * 32];
    __shared__ f16 Al[2][128 * 32];
    __shared__ f16 Bh[2][128 * 32];
    __shared__ f16 Bl[2][128 * 32];
    const int t = threadIdx.x;
    const int w = t >> 6, l = t & 63;
    const int m0 = blockIdx.y * 128, n0 = blockIdx.x * 128;
    const int wm = (w & 1) * 64, wn = (w >> 1) * 64;
    const int K2 = 2 * K;
    const int NK = K / 32;

    f32x4 acc[4][4];
    #pragma unroll
    for (int i = 0; i < 4; ++i)
        #pragma unroll
        for (int j = 0; j < 4; ++j) acc[i][j] = (f32x4){0.f, 0.f, 0.f, 0.f};

    const int srow = l >> 2;
    const int gq = ((l & 3) - (srow >> 1)) & 3;
    const int skoff = gq * 8;
    const int sqf = (((l >> 4) + (((l & 15) >> 1) & 3)) & 3) * 8;

    auto STAGE = [&](int buf, int kt) {
        int k0 = kt * 32;
        #pragma unroll
        for (int s = 0; s < 2; ++s) {
            int grp = w * 2 + s;
            int row = grp * 16 + srow;
            const f16* ap = Aw + (size_t)(m0 + row) * K2 + k0 + skoff;
            async_copy16(ap,     &Ah[buf][grp * 512 + l * 8]);
            async_copy16(ap + K, &Al[buf][grp * 512 + l * 8]);
            const f16* bp = Bw + (size_t)(n0 + row) * K2 + k0 + skoff;
            async_copy16(bp,     &Bh[buf][grp * 512 + l * 8]);
            async_copy16(bp + K, &Bl[buf][grp * 512 + l * 8]);
        }
    };

    STAGE(0, 0);
    __syncthreads();

    for (int kt = 0; kt < NK; ++kt) {
        int cur = kt & 1;
        if (kt + 1 < NK) STAGE(cur ^ 1, kt + 1);
        f16x8 afh[4], afl[4], bfh[4], bfl[4];
        #pragma unroll
        for (int i = 0; i < 4; ++i) {
            int base = (wm + i * 16 + (l & 15)) * 32 + sqf;
            afh[i] = *(const f16x8*)&Ah[cur][base];
            afl[i] = *(const f16x8*)&Al[cur][base];
        }
        #pragma unroll
        for (int j = 0; j < 4; ++j) {
            int base = (wn + j * 16 + (l & 15)) * 32 + sqf;
            bfh[j] = *(const f16x8*)&Bh[cur][base];
            bfl[j] = *(const f16x8*)&Bl[cur][base];
        }
        #pragma unroll
        for (int i = 0; i < 4; ++i)
            #pragma unroll
            for (int j = 0; j < 4; ++j) {
                acc[i][j] = __builtin_amdgcn_mfma_f32_16x16x32_f16(afh[i], bfh[j], acc[i][j], 0, 0, 0);
                acc[i][j] = __builtin_amdgcn_mfma_f32_16x16x32_f16(afl[i], bfh[j], acc[i][j], 0, 0, 0);
                acc[i][j] = __builtin_amdgcn_mfma_f32_16x16x32_f16(afh[i], bfl[j], acc[i][j], 0, 0, 0);
            }
        __syncthreads();
    }
    float bv[4];
    #pragma unroll
    for (int j = 0; j < 4; ++j)
        bv[j] = bias ? bias[n0 + wn + j * 16 + (l & 15)] : 0.f;
    #pragma unroll
    for (int i = 0; i < 4; ++i)
        #pragma unroll
        for (int j = 0; j < 4; ++j)
            #pragma unroll
            for (int r = 0; r < 4; ++r) {
                int m = m0 + wm + i * 16 + (l >> 4) * 4 + r;
                int n = n0 + wn + j * 16 + (l & 15);
                float v = acc[i][j][r] + bv[j];
                if (ADDC0) v += C0[(size_t)m * Ncols + n];
                if (TANH)  v = tanhf(v);
                C[(size_t)m * Ncols + n] = v;
            }
}

// Weight transpose + hi/lo split: W [K,N] fp32 -> Wt [N, hi(K)|lo(K)] f16.
__global__ __launch_bounds__(256) void wsplit_kernel(const float* __restrict__ W,
                                                     f16* __restrict__ Wt,
                                                     int K, int N)
{
    __shared__ float tile[64][65];
    const int t = threadIdx.x;
    const int kb = blockIdx.y * 64, nb = blockIdx.x * 64;
    #pragma unroll
    for (int i = 0; i < 4; ++i) {
        int r = (t >> 4) + i * 16;
        int c = (t & 15) * 4;
        *(float4*)&tile[r][c] = *(const float4*)&W[(size_t)(kb + r) * N + nb + c];
    }
    __syncthreads();
    const int r2 = t >> 2;
    const int kc = (t & 3) * 16;
    f16x8 h0, h1, lo0, lo1;
    #pragma unroll
    for (int e = 0; e < 8; ++e) {
        float x = tile[kc + e][r2];
        f16 hh = (f16)x; h0[e] = hh; lo0[e] = (f16)(x - (float)hh);
        float y = tile[kc + 8 + e][r2];
        f16 hh2 = (f16)y; h1[e] = hh2; lo1[e] = (f16)(y - (float)hh2);
    }
    f16* base = Wt + (size_t)(nb + r2) * 2 * K + kb + kc;
    *(f16x8*)base = h0; *(f16x8*)(base + 8) = h1;
    *(f16x8*)(base + K) = lo0; *(f16x8*)(base + K + 8) = lo1;
}

// b_comb[n] = sum_k b_dim[k] * W_fus[512+k][n] + b_fus[n]
__global__ __launch_bounds__(256) void bcomb_kernel(const float* __restrict__ b_dim,
                                                    const float* __restrict__ W_fus2,
                                                    const float* __restrict__ b_fus,
                                                    float* __restrict__ b_comb)
{
    int n = blockIdx.x * 256 + threadIdx.x;
    if (n >= DDIM) return;
    float s = b_fus[n];
    for (int k = 0; k < DDIM; ++k) s += b_dim[k] * W_fus2[(size_t)k * DDIM + n];
    b_comb[n] = s;
}

// fp32 GEMM (used only for the tiny W_comb2 = W_dim @ W_fus2 fold).
template<int ACT>
__global__ __launch_bounds__(256) void gemm_kernel(
    const float* __restrict__ A, int K1,
    const float* __restrict__ A2, int K2,
    const float* __restrict__ B, const float* __restrict__ bias,
    float* __restrict__ C, int Ncols)
{
    __shared__ float As[16][132];
    __shared__ float Bs[16][128];
    const int t = threadIdx.x;
    const int n0 = blockIdx.x * 128;
    const int m0 = blockIdx.y * 128;
    const int ty = t >> 4, tx = t & 15;
    const int K = K1 + K2;

    float acc[8][8];
    #pragma unroll
    for (int i = 0; i < 8; ++i)
        #pragma unroll
        for (int j = 0; j < 8; ++j) acc[i][j] = 0.f;

    const int ar = t >> 1;
    const int akc = (t & 1) * 8;
    const int bkr = t >> 4;
    const int bc = (t & 15) * 8;

    for (int k0 = 0; k0 < K; k0 += 16) {
        int kk = k0 + akc;
        float4 v0, v1;
        if (kk < K1) {
            const float* p = A + (size_t)(m0 + ar) * K1 + kk;
            v0 = *(const float4*)p; v1 = *(const float4*)(p + 4);
        } else {
            const float* p = A2 + (size_t)(m0 + ar) * K2 + (kk - K1);
            v0 = *(const float4*)p; v1 = *(const float4*)(p + 4);
        }
        const float* bp = B + (size_t)(k0 + bkr) * Ncols + n0 + bc;
        float4 w0 = *(const float4*)bp, w1 = *(const float4*)(bp + 4);
        __syncthreads();
        As[akc+0][ar] = v0.x; As[akc+1][ar] = v0.y; As[akc+2][ar] = v0.z; As[akc+3][ar] = v0.w;
        As[akc+4][ar] = v1.x; As[akc+5][ar] = v1.y; As[akc+6][ar] = v1.z; As[akc+7][ar] = v1.w;
        *(float4*)&Bs[bkr][bc] = w0; *(float4*)&Bs[bkr][bc + 4] = w1;
        __syncthreads();
        #pragma unroll
        for (int k = 0; k < 16; ++k) {
            float a[8], b[8];
            *(float4*)&a[0] = *(const float4*)&As[k][ty * 8];
            *(float4*)&a[4] = *(const float4*)&As[k][ty * 8 + 4];
            *(float4*)&b[0] = *(const float4*)&Bs[k][tx * 4];
            *(float4*)&b[4] = *(const float4*)&Bs[k][64 + tx * 4];
            #pragma unroll
            for (int i = 0; i < 8; ++i)
                #pragma unroll
                for (int j = 0; j < 8; ++j) acc[i][j] += a[i] * b[j];
        }
    }
    float4 bv0 = *(const float4*)(bias + n0 + tx * 4);
    float4 bv1 = *(const float4*)(bias + n0 + 64 + tx * 4);
    #pragma unroll
    for (int i = 0; i < 8; ++i) {
        int row = m0 + ty * 8 + i;
        float4 o0, o1;
        o0.x = acc[i][0] + bv0.x; o0.y = acc[i][1] + bv0.y;
        o0.z = acc[i][2] + bv0.z; o0.w = acc[i][3] + bv0.w;
        o1.x = acc[i][4] + bv1.x; o1.y = acc[i][5] + bv1.y;
        o1.z = acc[i][6] + bv1.z; o1.w = acc[i][7] + bv1.w;
        if (ACT == 1) {
            o0.x = tanhf(o0.x); o0.y = tanhf(o0.y); o0.z = tanhf(o0.z); o0.w = tanhf(o0.w);
            o1.x = tanhf(o1.x); o1.y = tanhf(o1.y); o1.z = tanhf(o1.z); o1.w = tanhf(o1.w);
        }
        *(float4*)(C + (size_t)row * Ncols + n0 + tx * 4) = o0;
        *(float4*)(C + (size_t)row * Ncols + n0 + 64 + tx * 4) = o1;
    }
}

__global__ __launch_bounds__(256) void bn_stats_kernel(const float* __restrict__ X,
                                                       float* __restrict__ sums)
{
    __shared__ float red[8][64];
    int lane = threadIdx.x & 63;
    int rl = threadIdx.x >> 6;
    int c = blockIdx.x * 64 + lane;
    int chunk = N_ROWS / gridDim.y;
    int rbeg = blockIdx.y * chunk;
    float s = 0.f, s2 = 0.f;
    for (int r = rbeg + rl; r < rbeg + chunk; r += 4) {
        float v = X[(size_t)r * DDIM + c];
        s += v; s2 += v * v;
    }
    red[rl][lane] = s; red[4 + rl][lane] = s2;
    __syncthreads();
    if (threadIdx.x < 64) {
        float ts = red[0][lane] + red[1][lane] + red[2][lane] + red[3][lane];
        float t2 = red[4][lane] + red[5][lane] + red[6][lane] + red[7][lane];
        atomicAdd(&sums[c], ts);
        atomicAdd(&sums[DDIM + c], t2);
    }
}

template<int TANH>
__global__ __launch_bounds__(256) void bn_apply_kernel(
    const float* __restrict__ X, float* __restrict__ Y,
    const float* __restrict__ sums, const float* __restrict__ g,
    const float* __restrict__ b, float invN)
{
    size_t i = (size_t)blockIdx.x * 256 + threadIdx.x;
    int cg = (int)(i % (DDIM / 4));
    int c = cg * 4;
    float4 x = ((const float4*)X)[i];
    float4 sm = *(const float4*)(sums + c);
    float4 sq = *(const float4*)(sums + DDIM + c);
    float4 gv = *(const float4*)(g + c);
    float4 bv = *(const float4*)(b + c);
    float m, var, rs;
    m = sm.x * invN; var = sq.x * invN - m * m; rs = rsqrtf(var + BN_EPS);
    x.x = (x.x - m) * rs * gv.x + bv.x;
    m = sm.y * invN; var = sq.y * invN - m * m; rs = rsqrtf(var + BN_EPS);
    x.y = (x.y - m) * rs * gv.y + bv.y;
    m = sm.z * invN; var = sq.z * invN - m * m; rs = rsqrtf(var + BN_EPS);
    x.z = (x.z - m) * rs * gv.z + bv.z;
    m = sm.w * invN; var = sq.w * invN - m * m; rs = rsqrtf(var + BN_EPS);
    x.w = (x.w - m) * rs * gv.w + bv.w;
    if (TANH) { x.x = tanhf(x.x); x.y = tanhf(x.y); x.z = tanhf(x.z); x.w = tanhf(x.w); }
    ((float4*)Y)[i] = x;
}

extern "C" void kernel_launch(void* const* d_in, const int* in_sizes, int n_in,
                              void* d_out, int out_size, void* d_ws, size_t ws_size,
                              hipStream_t stream)
{
    const float* src   = (const float*)d_in[0];
    const float* anc   = (const float*)d_in[1];
    const float* W_dim = (const float*)d_in[2];
    const float* b_dim = (const float*)d_in[3];
    const float* W_fus = (const float*)d_in[4];
    const float* b_fus = (const float*)d_in[5];
    const float* W_e1  = (const float*)d_in[6];
    const float* b_e1  = (const float*)d_in[7];
    const float* W_e2  = (const float*)d_in[8];
    const float* b_e2  = (const float*)d_in[9];
    const float* g1    = (const float*)d_in[10];
    const float* bt1   = (const float*)d_in[11];
    const float* g2    = (const float*)d_in[12];
    const float* bt2   = (const float*)d_in[13];
    const float* W_d   = (const float*)d_in[14];
    const float* b_d   = (const float*)d_in[15];
    const float* g_d   = (const float*)d_in[16];
    const float* bt_d  = (const float*)d_in[17];
    float* out = (float*)d_out;          // doubles as `comb`

    float* ws = (float*)d_ws;
    // Layout (floats).  Temporal sharing:
    //  dist phase:   score, src2q, anc2q, cand_n, norm_a, thrbuf, cnt, cand_i
    //  weight prep:  wbase (over src2q), W_comb2, zeros512, b_comb
    //  network:      hbuf (=score), aslot/h_h (28049408, time-shared), combh,
    //                sums1..3 (relocated into dead cand_i tail region)
    float* score  = ws;                        // 16384x1024 fp32 seed keys / h chunk
    float* bufA   = ws + 16777216;             // 16384x512 fp32 (neigh / t / bn2)
    char*  src2q  = (char*)(ws + 25165824);    // 16384x512 i8
    char*  anc2q  = (char*)(ws + 37748736);    // 8192x512 i8
    f16*   wbase  = (f16*)(ws + 25165824);     // weight overlay (after dist)
    f16*   Wt_fus1  = wbase;                   // [512, 1024]
    f16*   Wt_comb2 = wbase + 524288;          // [512, 1024]
    f16*   Wt_e1    = wbase + 1048576;         // [2048, 1024]
    f16*   Wt_e2    = wbase + 3145728;         // [512, 4096]
    f16*   Wt_d     = wbase + 5242880;         // [512, 1024]
    f16*   aslot    = (f16*)(ws + 28049408);   // 16384x1024 f16 A-splits (pre/post loop)
    f16*   h_h      = (f16*)(ws + 28049408);   // 8192x4096 f16 (loop only; shares aslot)
    f16*   combh    = (f16*)(ws + 44826624);   // 8192x1024 f16 (loop only)
    float* cand_n   = ws + 29360128;           // dist phase only (under h_h)
    float* W_comb2  = ws + 44040192;           // weight prep only (under h_h)
    float* norm_a   = ws + 44302336;           // dist phase only
    float* thrbuf   = ws + 44478464;           // dist phase only
    int*   cnt      = (int*)(ws + 44494848);   // dist phase only
    int*   cand_i   = (int*)(ws + 48705536);   // dist phase only
    float* sums1    = ws + 49020928;           // relocated (dead cand_i tail)
    float* sums2    = sums1 + 1024;
    float* sums3    = sums2 + 1024;
    float* zeros512 = ws + 49024000;
    float* b_comb   = ws + 49024512;

    const float invN = 1.0f / (float)N_ROWS;
    float* hbuf = score;   // network-phase alias

    zero_kernel<<<dim3(64), 256, 0, stream>>>((float*)cnt, 16384); // cnt = 0
    quant_i8_kernel<<<dim3(N_ROWS * DDIM / 1024), 256, 0, stream>>>(
        src, (unsigned int*)src2q, N_ROWS * DDIM / 4);
    quant_i8_kernel<<<dim3(M_ANCH * DDIM / 1024), 256, 0, stream>>>(
        anc, (unsigned int*)anc2q, M_ANCH * DDIM / 4);
    anchor_norm_kernel<<<dim3(M_ANCH / 4), 256, 0, stream>>>(anc, norm_a);

    // dist: approx seed keys -> margin threshold -> approx collect -> exact rescore
    gemm_i8<0><<<dim3(SEED / 128, N_ROWS / 128), 256, 0, stream>>>(
        src2q, anc2q, norm_a, nullptr, nullptr, nullptr, nullptr, 0, score, SEED);
    topk_scan_kernel<<<dim3(N_ROWS / 4), 256, 0, stream>>>(
        score, norm_a, thrbuf, cnt, cand_i, cand_n);
    gemm_i8<1><<<dim3((M_ANCH - SEED) / 128, N_ROWS / 128), 256, 0, stream>>>(
        src2q, anc2q + (size_t)SEED * DDIM, norm_a + SEED, thrbuf,
        cnt, cand_i, cand_n, SEED, nullptr, 0);
    rescore_kernel<<<dim3(N_ROWS / 4), 256, 0, stream>>>(
        src, anc, cnt, cand_i, cand_n, bufA);

    // sums/zeros live in dead dist-region: zero them only now
    zero_kernel<<<dim3(14), 256, 0, stream>>>(sums1, 3584);   // sums1..3 + zeros512

    // Weight prep (overlays dead src2q region)
    wsplit_kernel<<<dim3(DDIM / 64, DDIM / 64), 256, 0, stream>>>(W_fus, Wt_fus1, DDIM, DDIM);
    wsplit_kernel<<<dim3(FDIM / 64, DDIM / 64), 256, 0, stream>>>(W_e1, Wt_e1, DDIM, FDIM);
    wsplit_kernel<<<dim3(DDIM / 64, FDIM / 64), 256, 0, stream>>>(W_e2, Wt_e2, FDIM, DDIM);
    wsplit_kernel<<<dim3(DDIM / 64, DDIM / 64), 256, 0, stream>>>(W_d, Wt_d, DDIM, DDIM);
    gemm_kernel<0><<<dim3(4, 4), 256, 0, stream>>>(
        W_dim, DDIM, nullptr, 0, W_fus + DDIM * DDIM, zeros512, W_comb2, DDIM);
    bcomb_kernel<<<dim3(2), 256, 0, stream>>>(b_dim, W_fus + DDIM * DDIM, b_fus, b_comb);
    wsplit_kernel<<<dim3(DDIM / 64, DDIM / 64), 256, 0, stream>>>(W_comb2, Wt_comb2, DDIM, DDIM);

    // comb = src @ Wf1 + b_comb + neigh @ W_comb2   -> out, then BN1
    rowsplit_kernel<<<dim3(N_ROWS * DDIM / 1024), 256, 0, stream>>>(
        src, aslot, N_ROWS * DDIM / 4, 7);
    gemm_f16hl<0, 0, DDIM><<<dim3(DDIM / 128, N_ROWS / 128), 256, 0, stream>>>(
        aslot, Wt_fus1, b_comb, nullptr, out, DDIM);
    rowsplit_kernel<<<dim3(N_ROWS * DDIM / 1024), 256, 0, stream>>>(
        bufA, aslot, N_ROWS * DDIM / 4, 7);
    gemm_f16hl<1, 0, DDIM><<<dim3(DDIM / 128, N_ROWS / 128), 256, 0, stream>>>(
        aslot, Wt_comb2, nullptr, out, out, DDIM);
    bn_stats_kernel<<<dim3(DDIM / 64, 16), 256, 0, stream>>>(out, sums1);
    bn_apply_kernel<0><<<dim3(8192), 256, 0, stream>>>(out, out, sums1, g1, bt1, invN);

    // encoder, chunked: h = tanh(comb@We1+b1); t = h@We2 + b2 + comb
    for (int r0 = 0; r0 < N_ROWS; r0 += CHUNK) {
        rowsplit_kernel<<<dim3(CHUNK * DDIM / 1024), 256, 0, stream>>>(
            out + (size_t)r0 * DDIM, combh, CHUNK * DDIM / 4, 7);
        gemm_f16hl<0, 1, DDIM><<<dim3(FDIM / 128, CHUNK / 128), 256, 0, stream>>>(
            combh, Wt_e1, b_e1, nullptr, hbuf, FDIM);
        rowsplit_kernel<<<dim3(CHUNK * FDIM / 1024), 256, 0, stream>>>(
            hbuf, h_h, CHUNK * FDIM / 4, 9);
        gemm_f16hl<1, 0, FDIM><<<dim3(DDIM / 128, CHUNK / 128), 256, 0, stream>>>(
            h_h, Wt_e2, b_e2, out + (size_t)r0 * DDIM, bufA + (size_t)r0 * DDIM,
            DDIM);
    }
    bn_stats_kernel<<<dim3(DDIM / 64, 16), 256, 0, stream>>>(bufA, sums2);
    bn_apply_kernel<0><<<dim3(8192), 256, 0, stream>>>(bufA, bufA, sums2, g2, bt2, invN);

    // decoder -> out, BN3 + tanh
    rowsplit_kernel<<<dim3(N_ROWS * DDIM / 1024), 256, 0, stream>>>(
        bufA, aslot, N_ROWS * DDIM / 4, 7);
    gemm_f16hl<0, 0, DDIM><<<dim3(DDIM / 128, N_ROWS / 128), 256, 0, stream>>>(
        aslot, Wt_d, b_d, nullptr, out, DDIM);
    bn_stats_kernel<<<dim3(DDIM / 64, 16), 256, 0, stream>>>(out, sums3);
    bn_apply_kernel<1><<<dim3(8192), 256, 0, stream>>>(out, out, sums3, g_d, bt_d, invN);
}

// Round 10
// 1395.868 us; speedup vs baseline: 1.2256x; 1.2256x over previous
//
#include <hip/hip_runtime.h>
#include <math.h>

#define N_ROWS 16384
#define M_ANCH 8192
#define DDIM   512
#define FDIM   2048
#define KNN    5
#define BN_EPS 1e-5f
#define SEED   1024    // dist seed chunk (approx scan sets threshold)
#define CAND_MAX 256   // per-row candidate buffer (E~55 with margin, overflow P ~ 0)
#define MARGIN 6.0f    // covers i8 key-error (sigma~0.66 per key, 6.4 sigma for pair)
#define QSCALE 28.0f   // i8 quant scale: clip at 127/28 = 4.54 sigma
#define TWO_INV_S2 (2.0f / (QSCALE * QSCALE))

typedef _Float16 f16;
typedef _Float16 f16x8 __attribute__((ext_vector_type(8)));
typedef _Float16 f16x4 __attribute__((ext_vector_type(4)));
typedef float f32x4 __attribute__((ext_vector_type(4)));
typedef int   i32x4 __attribute__((ext_vector_type(4)));

__device__ __forceinline__ void async_copy16(const void* g, void* l) {
    __builtin_amdgcn_global_load_lds(
        (const __attribute__((address_space(1))) void*)g,
        (__attribute__((address_space(3))) void*)l, 16, 0, 0);
}

__device__ __forceinline__ bool kless(float k1, int i1, float k2, int i2) {
    return (k1 < k2) || (k1 == k2 && i1 < i2);
}

__device__ __forceinline__ void insert5(float (&bk)[KNN], int (&bi)[KNN], float key, int id) {
    if (!kless(key, id, bk[4], bi[4])) return;
    bool c3 = kless(key, id, bk[3], bi[3]);
    bool c2 = kless(key, id, bk[2], bi[2]);
    bool c1 = kless(key, id, bk[1], bi[1]);
    bool c0 = kless(key, id, bk[0], bi[0]);
    bk[4] = c3 ? bk[3] : key;                  bi[4] = c3 ? bi[3] : id;
    bk[3] = c3 ? (c2 ? bk[2] : key) : bk[3];   bi[3] = c3 ? (c2 ? bi[2] : id) : bi[3];
    bk[2] = c2 ? (c1 ? bk[1] : key) : bk[2];   bi[2] = c2 ? (c1 ? bi[1] : id) : bi[2];
    bk[1] = c1 ? (c0 ? bk[0] : key) : bk[1];   bi[1] = c1 ? (c0 ? bi[0] : id) : bi[1];
    bk[0] = c0 ? key : bk[0];                  bi[0] = c0 ? id : bi[0];
}

__global__ void zero_kernel(float* p, int n) {
    int i = blockIdx.x * blockDim.x + threadIdx.x;
    if (i < n) p[i] = 0.f;
}

// fp32 -> i8 quant (round-nearest, clamp +-127), 4 elems -> packed u32.
__global__ __launch_bounds__(256) void quant_i8_kernel(const float* __restrict__ X,
                                                       unsigned int* __restrict__ Y, int n4) {
    int i = blockIdx.x * 256 + threadIdx.x;
    if (i >= n4) return;
    float4 v = ((const float4*)X)[i];
    int a = (int)rintf(v.x * QSCALE); a = a > 127 ? 127 : (a < -127 ? -127 : a);
    int b = (int)rintf(v.y * QSCALE); b = b > 127 ? 127 : (b < -127 ? -127 : b);
    int c = (int)rintf(v.z * QSCALE); c = c > 127 ? 127 : (c < -127 ? -127 : c);
    int d = (int)rintf(v.w * QSCALE); d = d > 127 ? 127 : (d < -127 ? -127 : d);
    Y[i] = (unsigned int)(a & 255) | ((unsigned int)(b & 255) << 8)
         | ((unsigned int)(c & 255) << 16) | ((unsigned int)(d & 255) << 24);
}

// fp32 -> f16 plain cast (network A operands; W stays hi/lo-compensated).
__global__ __launch_bounds__(256) void cast_f16_kernel(const float* __restrict__ X,
                                                       f16* __restrict__ Y, int n4) {
    int i = blockIdx.x * 256 + threadIdx.x;
    if (i >= n4) return;
    float4 v = ((const float4*)X)[i];
    f16x4 h;
    h.x = (f16)v.x; h.y = (f16)v.y; h.z = (f16)v.z; h.w = (f16)v.w;
    ((f16x4*)Y)[i] = h;
}

__global__ __launch_bounds__(256) void anchor_norm_kernel(const float* __restrict__ a,
                                                          float* __restrict__ norm_a) {
    int wave = threadIdx.x >> 6, lane = threadIdx.x & 63;
    int row = blockIdx.x * 4 + wave;
    const float4* ar = (const float4*)(a + (size_t)row * DDIM);
    float4 v1 = ar[lane * 2];
    float4 v2 = ar[lane * 2 + 1];
    float s = v1.x*v1.x + v1.y*v1.y + v1.z*v1.z + v1.w*v1.w
            + v2.x*v2.x + v2.y*v2.y + v2.z*v2.z + v2.w*v2.w;
    for (int off = 32; off; off >>= 1) s += __shfl_xor(s, off, 64);
    if (lane == 0) norm_a[row] = s;
}

// i8 dist GEMM, double-buffered LDS (one barrier/K-step).
// COLLECT==0: writes key = norm[n] - 2*dot/S^2 to C (seed scan input).
// COLLECT==1: appends (id, exact norm) with key < thr[row] to candidate lists.
template<int COLLECT>
__global__ __launch_bounds__(256) void gemm_i8(
    const char* __restrict__ A, const char* __restrict__ B,
    const float* __restrict__ norm, const float* __restrict__ thr,
    int* __restrict__ cnt, int* __restrict__ cand_i, float* __restrict__ cand_n,
    int idofs, float* __restrict__ C, int Ncols)
{
    __shared__ char As[2][128 * 64];
    __shared__ char Bs[2][128 * 64];
    const int t = threadIdx.x;
    const int w = t >> 6, l = t & 63;
    const int m0 = blockIdx.y * 128, n0 = blockIdx.x * 128;
    const int wm = (w & 1) * 64, wn = (w >> 1) * 64;

    i32x4 acc[4][4];
    #pragma unroll
    for (int i = 0; i < 4; ++i)
        #pragma unroll
        for (int j = 0; j < 4; ++j) acc[i][j] = (i32x4){0, 0, 0, 0};

    const int srow = l >> 2;
    const int gq = ((l & 3) - (srow >> 1)) & 3;
    const int skoff = gq * 16;
    const int sqf = (((l >> 4) + (((l & 15) >> 1) & 3)) & 3) * 16;

    auto STAGE = [&](int buf, int kt) {
        int k0 = kt * 64;
        #pragma unroll
        for (int s = 0; s < 2; ++s) {
            int grp = w * 2 + s;
            int row = grp * 16 + srow;
            async_copy16(A + (size_t)(m0 + row) * DDIM + k0 + skoff,
                         &As[buf][grp * 1024 + l * 16]);
            async_copy16(B + (size_t)(n0 + row) * DDIM + k0 + skoff,
                         &Bs[buf][grp * 1024 + l * 16]);
        }
    };

    STAGE(0, 0);
    __syncthreads();

    for (int kt = 0; kt < 8; ++kt) {
        int cur = kt & 1;
        if (kt < 7) STAGE(cur ^ 1, kt + 1);
        i32x4 af[4], bf[4];
        #pragma unroll
        for (int i = 0; i < 4; ++i)
            af[i] = *(const i32x4*)&As[cur][(wm + i * 16 + (l & 15)) * 64 + sqf];
        #pragma unroll
        for (int j = 0; j < 4; ++j)
            bf[j] = *(const i32x4*)&Bs[cur][(wn + j * 16 + (l & 15)) * 64 + sqf];
        #pragma unroll
        for (int i = 0; i < 4; ++i)
            #pragma unroll
            for (int j = 0; j < 4; ++j)
                acc[i][j] = __builtin_amdgcn_mfma_i32_16x16x64_i8(af[i], bf[j], acc[i][j], 0, 0, 0);
        __syncthreads();
    }

    float nj[4];
    #pragma unroll
    for (int j = 0; j < 4; ++j) nj[j] = norm[n0 + wn + j * 16 + (l & 15)];

    if (COLLECT) {
        float thr4[4][4];
        #pragma unroll
        for (int i = 0; i < 4; ++i) {
            float4 tv = *(const float4*)&thr[m0 + wm + i * 16 + (l >> 4) * 4];
            thr4[i][0] = tv.x; thr4[i][1] = tv.y; thr4[i][2] = tv.z; thr4[i][3] = tv.w;
        }
        #pragma unroll
        for (int i = 0; i < 4; ++i)
            #pragma unroll
            for (int j = 0; j < 4; ++j)
                #pragma unroll
                for (int r = 0; r < 4; ++r) {
                    float key = nj[j] - TWO_INV_S2 * (float)acc[i][j][r];
                    if (key < thr4[i][r]) {
                        int row = m0 + wm + i * 16 + (l >> 4) * 4 + r;
                        int pos = atomicAdd(&cnt[row], 1);
                        if (pos < CAND_MAX) {
                            cand_i[(size_t)row * CAND_MAX + pos] =
                                idofs + n0 + wn + j * 16 + (l & 15);
                            cand_n[(size_t)row * CAND_MAX + pos] = nj[j];
                        }
                    }
                }
    } else {
        #pragma unroll
        for (int i = 0; i < 4; ++i)
            #pragma unroll
            for (int j = 0; j < 4; ++j)
                #pragma unroll
                for (int r = 0; r < 4; ++r) {
                    int m = m0 + wm + i * 16 + (l >> 4) * 4 + r;
                    int n = n0 + wn + j * 16 + (l & 15);
                    C[(size_t)m * Ncols + n] = nj[j] - TWO_INV_S2 * (float)acc[i][j][r];
                }
    }
}

// approx top-5 over seed keys -> thrbuf = 5th-best + MARGIN; appends all seed
// (id, exact norm) with key < thr to the candidate list (includes the top-5).
__global__ __launch_bounds__(256) void topk_scan_kernel(
    const float* __restrict__ g, const float* __restrict__ norm_a,
    float* __restrict__ thrbuf, int* __restrict__ cnt,
    int* __restrict__ cand_i, float* __restrict__ cand_n)
{
    int row = blockIdx.x * 4 + (threadIdx.x >> 6);
    int lane = threadIdx.x & 63;
    const float* grow = g + (size_t)row * SEED;
    float4 v0 = *(const float4*)(grow + lane * 4);
    float4 v1 = *(const float4*)(grow + 256 + lane * 4);
    float4 v2 = *(const float4*)(grow + 512 + lane * 4);
    float4 v3 = *(const float4*)(grow + 768 + lane * 4);
    float bk[KNN]; int bi[KNN];
    #pragma unroll
    for (int q = 0; q < KNN; ++q) { bk[q] = 3.0e38f; bi[q] = 0x7fffffff; }
    int c = lane * 4;
    insert5(bk, bi, v0.x, c);       insert5(bk, bi, v0.y, c + 1);
    insert5(bk, bi, v0.z, c + 2);   insert5(bk, bi, v0.w, c + 3);
    insert5(bk, bi, v1.x, c + 256); insert5(bk, bi, v1.y, c + 257);
    insert5(bk, bi, v1.z, c + 258); insert5(bk, bi, v1.w, c + 259);
    insert5(bk, bi, v2.x, c + 512); insert5(bk, bi, v2.y, c + 513);
    insert5(bk, bi, v2.z, c + 514); insert5(bk, bi, v2.w, c + 515);
    insert5(bk, bi, v3.x, c + 768); insert5(bk, bi, v3.y, c + 769);
    insert5(bk, bi, v3.z, c + 770); insert5(bk, bi, v3.w, c + 771);
    for (int off = 32; off >= 1; off >>= 1) {
        float ok[KNN]; int oi[KNN];
        #pragma unroll
        for (int q = 0; q < KNN; ++q) {
            ok[q] = __shfl_xor(bk[q], off, 64);
            oi[q] = __shfl_xor(bi[q], off, 64);
        }
        #pragma unroll
        for (int q = 0; q < KNN; ++q) insert5(bk, bi, ok[q], oi[q]);
    }
    float thr = bk[4] + MARGIN;
    if (lane == 0) thrbuf[row] = thr;
    int* rci = cand_i + (size_t)row * CAND_MAX;
    float* rcn = cand_n + (size_t)row * CAND_MAX;
    #define PUSH(v, id) if ((v) < thr) { int pos = atomicAdd(&cnt[row], 1); \
                                         if (pos < CAND_MAX) { rci[pos] = (id); \
                                         rcn[pos] = norm_a[(id)]; } }
    PUSH(v0.x, c)       PUSH(v0.y, c + 1)   PUSH(v0.z, c + 2)   PUSH(v0.w, c + 3)
    PUSH(v1.x, c + 256) PUSH(v1.y, c + 257) PUSH(v1.z, c + 258) PUSH(v1.w, c + 259)
    PUSH(v2.x, c + 512) PUSH(v2.y, c + 513) PUSH(v2.z, c + 514) PUSH(v2.w, c + 515)
    PUSH(v3.x, c + 768) PUSH(v3.y, c + 769) PUSH(v3.z, c + 770) PUSH(v3.w, c + 771)
    #undef PUSH
}

// exact fp32 rescore + fused gather/mean (R9-verified: one wave per row,
// conflict-free swizzled PREF, unconditional vmcnt(4)).
__global__ __launch_bounds__(256) void rescore_kernel(
    const float* __restrict__ src, const float* __restrict__ anchor,
    const int* __restrict__ cnt, const int* __restrict__ cand_i,
    const float* __restrict__ cand_n, float* __restrict__ neigh)
{
    __shared__ float lb[4][2][DDIM];   // [wave][dbuf][elem] = 16 KB
    int wv = threadIdx.x >> 6, lane = threadIdx.x & 63;
    int row = blockIdx.x * 4 + wv;
    const float4* sp = (const float4*)(src + (size_t)row * DDIM);
    float4 s0 = sp[lane * 2], s1 = sp[lane * 2 + 1];
    int c = cnt[row]; if (c > CAND_MAX) c = CAND_MAX;   // c >= 5 always
    const int* ci = cand_i + (size_t)row * CAND_MAX;
    const float* cn = cand_n + (size_t)row * CAND_MAX;

    float bk[KNN]; int bi[KNN];
    #pragma unroll
    for (int q = 0; q < KNN; ++q) { bk[q] = 3.0e38f; bi[q] = 0x7fffffff; }

    auto PREF = [&](int buf, int id) {
        const float* gp = anchor + (size_t)id * DDIM;
        async_copy16(gp + lane * 8,     &lb[wv][buf][lane * 4]);
        async_copy16(gp + lane * 8 + 4, &lb[wv][buf][256 + lane * 4]);
    };

    int   id_c = ci[0];          float n_c = cn[0];
    int   id_n = ci[1];          float n_n = cn[1];
    PREF(0, id_c);
    PREF(1, id_n);

    for (int p = 0; p < c; ++p) {
        int id_f = 0; float n_f = 0.f;
        if (p + 2 < c) { id_f = ci[p + 2]; n_f = cn[p + 2]; }
        asm volatile("s_waitcnt vmcnt(4)" ::: "memory");
        const float* bc = &lb[wv][p & 1][0];
        float4 a0 = *(const float4*)&bc[lane * 4];        // elems [8l, 8l+4)
        float4 a1 = *(const float4*)&bc[256 + lane * 4];  // elems [8l+4, 8l+8)
        float d = s0.x*a0.x + s0.y*a0.y + s0.z*a0.z + s0.w*a0.w
                + s1.x*a1.x + s1.y*a1.y + s1.z*a1.z + s1.w*a1.w;
        #pragma unroll
        for (int off = 32; off; off >>= 1) d += __shfl_xor(d, off, 64);
        insert5(bk, bi, n_c - 2.f * d, id_c);
        if (p + 2 < c) PREF(p & 1, id_f);
        id_c = id_n; n_c = n_n;
        id_n = id_f; n_n = n_f;
    }

    const float4* a0 = (const float4*)(anchor + (size_t)bi[0] * DDIM);
    const float4* a1 = (const float4*)(anchor + (size_t)bi[1] * DDIM);
    const float4* a2 = (const float4*)(anchor + (size_t)bi[2] * DDIM);
    const float4* a3 = (const float4*)(anchor + (size_t)bi[3] * DDIM);
    const float4* a4 = (const float4*)(anchor + (size_t)bi[4] * DDIM);
    float4* np = (float4*)(neigh + (size_t)row * DDIM);
    #pragma unroll
    for (int p = 0; p < 2; ++p) {
        int c4 = lane + 64 * p;
        float4 v0 = a0[c4], v1 = a1[c4], v2 = a2[c4], v3 = a3[c4], v4 = a4[c4];
        float4 o;
        o.x = (v0.x + v1.x + v2.x + v3.x + v4.x) * 0.2f;
        o.y = (v0.y + v1.y + v2.y + v3.y + v4.y) * 0.2f;
        o.z = (v0.z + v1.z + v2.z + v3.z + v4.z) * 0.2f;
        o.w = (v0.w + v1.w + v2.w + v3.w + v4.w) * 0.2f;
        np[c4] = o;
    }
}

// Network GEMM v4: C = act(Af16 @ BwT + bias [+ C0]).
// A is PLAIN f16 [M,K] (activation rounding uncompensated: dropped Al*Bh term
// contributes ~2e-4 abs pre-BN, negligible vs 0.02 threshold).  B stays
// hi/lo [N, hi(K)|lo(K)] so weight quantization is exactly compensated:
// 2 MFMA per fragment pair (af*bh + af*bl).  Same verified one-barrier dbuf
// pipeline as gemm_i8.  LDS 48KB -> 3 blocks/CU.
// WF16: epilogue writes C as plain f16 (feeds the next GEMM directly).
template<int ADDC0, int TANH, int WF16, int K>
__global__ __launch_bounds__(256) void gemm_f16a(
    const f16* __restrict__ Aw, const f16* __restrict__ Bw,
    const float* __restrict__ bias, const float* __restrict__ C0,
    void* __restrict__ Cv, int Ncols)
{
    __shared__ f16 Ah[2][128 * 32];
    __shared__ f16 Bh[2][128 * 32];
    __shared__ f16 Bl[2][128 * 32];
    const int t = threadIdx.x;
    const int w = t >> 6, l = t & 63;
    const int m0 = blockIdx.y * 128, n0 = blockIdx.x * 128;
    const int wm = (w & 1) * 64, wn = (w >> 1) * 64;
    const int K2 = 2 * K;
    const int NK = K / 32;

    f32x4 acc[4][4];
    #pragma unroll
    for (int i = 0; i < 4; ++i)
        #pragma unroll
        for (int j = 0; j < 4; ++j) acc[i][j] = (f32x4){0.f, 0.f, 0.f, 0.f};

    const int srow = l >> 2;
    const int gq = ((l & 3) - (srow >> 1)) & 3;
    const int skoff = gq * 8;
    const int sqf = (((l >> 4) + (((l & 15) >> 1) & 3)) & 3) * 8;

    auto STAGE = [&](int buf, int kt) {
        int k0 = kt * 32;
        #pragma unroll
        for (int s = 0; s < 2; ++s) {
            int grp = w * 2 + s;
            int row = grp * 16 + srow;
            async_copy16(Aw + (size_t)(m0 + row) * K + k0 + skoff,
                         &Ah[buf][grp * 512 + l * 8]);
            const f16* bp = Bw + (size_t)(n0 + row) * K2 + k0 + skoff;
            async_copy16(bp,     &Bh[buf][grp * 512 + l * 8]);
            async_copy16(bp + K, &Bl[buf][grp * 512 + l * 8]);
        }
    };

    STAGE(0, 0);
    __syncthreads();

    for (int kt = 0; kt < NK; ++kt) {
        int cur = kt & 1;
        if (kt + 1 < NK) STAGE(cur ^ 1, kt + 1);
        f16x8 af[4], bfh[4], bfl[4];
        #pragma unroll
        for (int i = 0; i < 4; ++i)
            af[i] = *(const f16x8*)&Ah[cur][(wm + i * 16 + (l & 15)) * 32 + sqf];
        #pragma unroll
        for (int j = 0; j < 4; ++j) {
            int base = (wn + j * 16 + (l & 15)) * 32 + sqf;
            bfh[j] = *(const f16x8*)&Bh[cur][base];
            bfl[j] = *(const f16x8*)&Bl[cur][base];
        }
        #pragma unroll
        for (int i = 0; i < 4; ++i)
            #pragma unroll
            for (int j = 0; j < 4; ++j) {
                acc[i][j] = __builtin_amdgcn_mfma_f32_16x16x32_f16(af[i], bfh[j], acc[i][j], 0, 0, 0);
                acc[i][j] = __builtin_amdgcn_mfma_f32_16x16x32_f16(af[i], bfl[j], acc[i][j], 0, 0, 0);
            }
        __syncthreads();
    }
    float bv[4];
    #pragma unroll
    for (int j = 0; j < 4; ++j)
        bv[j] = bias ? bias[n0 + wn + j * 16 + (l & 15)] : 0.f;
    #pragma unroll
    for (int i = 0; i < 4; ++i)
        #pragma unroll
        for (int j = 0; j < 4; ++j)
            #pragma unroll
            for (int r = 0; r < 4; ++r) {
                int m = m0 + wm + i * 16 + (l >> 4) * 4 + r;
                int n = n0 + wn + j * 16 + (l & 15);
                float v = acc[i][j][r] + bv[j];
                if (ADDC0) v += C0[(size_t)m * Ncols + n];
                if (TANH)  v = tanhf(v);
                if (WF16)  ((f16*)Cv)[(size_t)m * Ncols + n] = (f16)v;
                else       ((float*)Cv)[(size_t)m * Ncols + n] = v;
            }
}

// Weight transpose + hi/lo split: W [K,N] fp32 -> Wt [N, hi(K)|lo(K)] f16.
__global__ __launch_bounds__(256) void wsplit_kernel(const float* __restrict__ W,
                                                     f16* __restrict__ Wt,
                                                     int K, int N)
{
    __shared__ float tile[64][65];
    const int t = threadIdx.x;
    const int kb = blockIdx.y * 64, nb = blockIdx.x * 64;
    #pragma unroll
    for (int i = 0; i < 4; ++i) {
        int r = (t >> 4) + i * 16;
        int c = (t & 15) * 4;
        *(float4*)&tile[r][c] = *(const float4*)&W[(size_t)(kb + r) * N + nb + c];
    }
    __syncthreads();
    const int r2 = t >> 2;
    const int kc = (t & 3) * 16;
    f16x8 h0, h1, lo0, lo1;
    #pragma unroll
    for (int e = 0; e < 8; ++e) {
        float x = tile[kc + e][r2];
        f16 hh = (f16)x; h0[e] = hh; lo0[e] = (f16)(x - (float)hh);
        float y = tile[kc + 8 + e][r2];
        f16 hh2 = (f16)y; h1[e] = hh2; lo1[e] = (f16)(y - (float)hh2);
    }
    f16* base = Wt + (size_t)(nb + r2) * 2 * K + kb + kc;
    *(f16x8*)base = h0; *(f16x8*)(base + 8) = h1;
    *(f16x8*)(base + K) = lo0; *(f16x8*)(base + K + 8) = lo1;
}

// b_comb[n] = sum_k b_dim[k] * W_fus[512+k][n] + b_fus[n]
__global__ __launch_bounds__(256) void bcomb_kernel(const float* __restrict__ b_dim,
                                                    const float* __restrict__ W_fus2,
                                                    const float* __restrict__ b_fus,
                                                    float* __restrict__ b_comb)
{
    int n = blockIdx.x * 256 + threadIdx.x;
    if (n >= DDIM) return;
    float s = b_fus[n];
    for (int k = 0; k < DDIM; ++k) s += b_dim[k] * W_fus2[(size_t)k * DDIM + n];
    b_comb[n] = s;
}

// fp32 GEMM (used only for the tiny W_comb2 = W_dim @ W_fus2 fold).
template<int ACT>
__global__ __launch_bounds__(256) void gemm_kernel(
    const float* __restrict__ A, int K1,
    const float* __restrict__ A2, int K2,
    const float* __restrict__ B, const float* __restrict__ bias,
    float* __restrict__ C, int Ncols)
{
    __shared__ float As[16][132];
    __shared__ float Bs[16][128];
    const int t = threadIdx.x;
    const int n0 = blockIdx.x * 128;
    const int m0 = blockIdx.y * 128;
    const int ty = t >> 4, tx = t & 15;
    const int K = K1 + K2;

    float acc[8][8];
    #pragma unroll
    for (int i = 0; i < 8; ++i)
        #pragma unroll
        for (int j = 0; j < 8; ++j) acc[i][j] = 0.f;

    const int ar = t >> 1;
    const int akc = (t & 1) * 8;
    const int bkr = t >> 4;
    const int bc = (t & 15) * 8;

    for (int k0 = 0; k0 < K; k0 += 16) {
        int kk = k0 + akc;
        float4 v0, v1;
        if (kk < K1) {
            const float* p = A + (size_t)(m0 + ar) * K1 + kk;
            v0 = *(const float4*)p; v1 = *(const float4*)(p + 4);
        } else {
            const float* p = A2 + (size_t)(m0 + ar) * K2 + (kk - K1);
            v0 = *(const float4*)p; v1 = *(const float4*)(p + 4);
        }
        const float* bp = B + (size_t)(k0 + bkr) * Ncols + n0 + bc;
        float4 w0 = *(const float4*)bp, w1 = *(const float4*)(bp + 4);
        __syncthreads();
        As[akc+0][ar] = v0.x; As[akc+1][ar] = v0.y; As[akc+2][ar] = v0.z; As[akc+3][ar] = v0.w;
        As[akc+4][ar] = v1.x; As[akc+5][ar] = v1.y; As[akc+6][ar] = v1.z; As[akc+7][ar] = v1.w;
        *(float4*)&Bs[bkr][bc] = w0; *(float4*)&Bs[bkr][bc + 4] = w1;
        __syncthreads();
        #pragma unroll
        for (int k = 0; k < 16; ++k) {
            float a[8], b[8];
            *(float4*)&a[0] = *(const float4*)&As[k][ty * 8];
            *(float4*)&a[4] = *(const float4*)&As[k][ty * 8 + 4];
            *(float4*)&b[0] = *(const float4*)&Bs[k][tx * 4];
            *(float4*)&b[4] = *(const float4*)&Bs[k][64 + tx * 4];
            #pragma unroll
            for (int i = 0; i < 8; ++i)
                #pragma unroll
                for (int j = 0; j < 8; ++j) acc[i][j] += a[i] * b[j];
        }
    }
    float4 bv0 = *(const float4*)(bias + n0 + tx * 4);
    float4 bv1 = *(const float4*)(bias + n0 + 64 + tx * 4);
    #pragma unroll
    for (int i = 0; i < 8; ++i) {
        int row = m0 + ty * 8 + i;
        float4 o0, o1;
        o0.x = acc[i][0] + bv0.x; o0.y = acc[i][1] + bv0.y;
        o0.z = acc[i][2] + bv0.z; o0.w = acc[i][3] + bv0.w;
        o1.x = acc[i][4] + bv1.x; o1.y = acc[i][5] + bv1.y;
        o1.z = acc[i][6] + bv1.z; o1.w = acc[i][7] + bv1.w;
        if (ACT == 1) {
            o0.x = tanhf(o0.x); o0.y = tanhf(o0.y); o0.z = tanhf(o0.z); o0.w = tanhf(o0.w);
            o1.x = tanhf(o1.x); o1.y = tanhf(o1.y); o1.z = tanhf(o1.z); o1.w = tanhf(o1.w);
        }
        *(float4*)(C + (size_t)row * Ncols + n0 + tx * 4) = o0;
        *(float4*)(C + (size_t)row * Ncols + n0 + 64 + tx * 4) = o1;
    }
}

__global__ __launch_bounds__(256) void bn_stats_kernel(const float* __restrict__ X,
                                                       float* __restrict__ sums)
{
    __shared__ float red[8][64];
    int lane = threadIdx.x & 63;
    int rl = threadIdx.x >> 6;
    int c = blockIdx.x * 64 + lane;
    int chunk = N_ROWS / gridDim.y;
    int rbeg = blockIdx.y * chunk;
    float s = 0.f, s2 = 0.f;
    for (int r = rbeg + rl; r < rbeg + chunk; r += 4) {
        float v = X[(size_t)r * DDIM + c];
        s += v; s2 += v * v;
    }
    red[rl][lane] = s; red[4 + rl][lane] = s2;
    __syncthreads();
    if (threadIdx.x < 64) {
        float ts = red[0][lane] + red[1][lane] + red[2][lane] + red[3][lane];
        float t2 = red[4][lane] + red[5][lane] + red[6][lane] + red[7][lane];
        atomicAdd(&sums[c], ts);
        atomicAdd(&sums[DDIM + c], t2);
    }
}

// BN apply; optionally also emits a plain-f16 copy (feeds the next GEMM's A).
template<int TANH>
__global__ __launch_bounds__(256) void bn_apply_kernel(
    const float* __restrict__ X, float* __restrict__ Y, f16* __restrict__ Yh,
    const float* __restrict__ sums, const float* __restrict__ g,
    const float* __restrict__ b, float invN)
{
    size_t i = (size_t)blockIdx.x * 256 + threadIdx.x;
    int cg = (int)(i % (DDIM / 4));
    int c = cg * 4;
    float4 x = ((const float4*)X)[i];
    float4 sm = *(const float4*)(sums + c);
    float4 sq = *(const float4*)(sums + DDIM + c);
    float4 gv = *(const float4*)(g + c);
    float4 bv = *(const float4*)(b + c);
    float m, var, rs;
    m = sm.x * invN; var = sq.x * invN - m * m; rs = rsqrtf(var + BN_EPS);
    x.x = (x.x - m) * rs * gv.x + bv.x;
    m = sm.y * invN; var = sq.y * invN - m * m; rs = rsqrtf(var + BN_EPS);
    x.y = (x.y - m) * rs * gv.y + bv.y;
    m = sm.z * invN; var = sq.z * invN - m * m; rs = rsqrtf(var + BN_EPS);
    x.z = (x.z - m) * rs * gv.z + bv.z;
    m = sm.w * invN; var = sq.w * invN - m * m; rs = rsqrtf(var + BN_EPS);
    x.w = (x.w - m) * rs * gv.w + bv.w;
    if (TANH) { x.x = tanhf(x.x); x.y = tanhf(x.y); x.z = tanhf(x.z); x.w = tanhf(x.w); }
    ((float4*)Y)[i] = x;
    if (Yh) {
        f16x4 h;
        h.x = (f16)x.x; h.y = (f16)x.y; h.z = (f16)x.z; h.w = (f16)x.w;
        ((f16x4*)Yh)[i] = h;
    }
}

extern "C" void kernel_launch(void* const* d_in, const int* in_sizes, int n_in,
                              void* d_out, int out_size, void* d_ws, size_t ws_size,
                              hipStream_t stream)
{
    const float* src   = (const float*)d_in[0];
    const float* anc   = (const float*)d_in[1];
    const float* W_dim = (const float*)d_in[2];
    const float* b_dim = (const float*)d_in[3];
    const float* W_fus = (const float*)d_in[4];
    const float* b_fus = (const float*)d_in[5];
    const float* W_e1  = (const float*)d_in[6];
    const float* b_e1  = (const float*)d_in[7];
    const float* W_e2  = (const float*)d_in[8];
    const float* b_e2  = (const float*)d_in[9];
    const float* g1    = (const float*)d_in[10];
    const float* bt1   = (const float*)d_in[11];
    const float* g2    = (const float*)d_in[12];
    const float* bt2   = (const float*)d_in[13];
    const float* W_d   = (const float*)d_in[14];
    const float* b_d   = (const float*)d_in[15];
    const float* g_d   = (const float*)d_in[16];
    const float* bt_d  = (const float*)d_in[17];
    float* out = (float*)d_out;          // doubles as `comb`

    float* ws = (float*)d_ws;
    // Layout (floats).  Temporal sharing:
    //  dist:    score(0), src2q(25165824), anc2q(37748736), cand_n(29360128),
    //           norm_a/thrbuf/cnt/cand_i (44302336+)
    //  weights: wbase over src2q (25165824..28049408), W_comb2(44040192)
    //  network: hH f16 over score (0..16777216), bufA(16777216), out,
    //           srcH(28049408), aH(32243712), combH(36438016),
    //           sums/zeros/b_comb (49020928+, dead cand_i tail)
    float* score  = ws;                        // seed keys (dist) / hH f16 (network)
    float* bufA   = ws + 16777216;             // 16384x512 fp32 (neigh / t / bn2)
    char*  src2q  = (char*)(ws + 25165824);
    char*  anc2q  = (char*)(ws + 37748736);
    f16*   wbase  = (f16*)(ws + 25165824);
    f16*   Wt_fus1  = wbase;                   // [512, 1024]
    f16*   Wt_comb2 = wbase + 524288;          // [512, 1024]
    f16*   Wt_e1    = wbase + 1048576;         // [2048, 1024]
    f16*   Wt_e2    = wbase + 3145728;         // [512, 4096]
    f16*   Wt_d     = wbase + 5242880;         // [512, 1024]
    f16*   hH       = (f16*)ws;                // 16384x2048 f16 (64MB, over score)
    f16*   srcH     = (f16*)(ws + 28049408);   // 16384x512 f16
    f16*   aH       = (f16*)(ws + 32243712);   // 16384x512 f16 (neigh / decoder in)
    f16*   combH    = (f16*)(ws + 36438016);   // 16384x512 f16
    float* cand_n   = ws + 29360128;           // dist phase only (under srcH? no:
                                               // srcH ends 32243712; cand_n is
                                               // 29360128..33554432 -- OVERLAP is
                                               // fine: cand_n dead before srcH use)
    float* W_comb2  = ws + 44040192;
    float* norm_a   = ws + 44302336;
    float* thrbuf   = ws + 44478464;
    int*   cnt      = (int*)(ws + 44494848);
    int*   cand_i   = (int*)(ws + 48705536);
    float* sums1    = ws + 49020928;
    float* sums2    = sums1 + 1024;
    float* sums3    = sums2 + 1024;
    float* zeros512 = ws + 49024000;
    float* b_comb   = ws + 49024512;

    const float invN = 1.0f / (float)N_ROWS;

    zero_kernel<<<dim3(64), 256, 0, stream>>>((float*)cnt, 16384); // cnt = 0
    quant_i8_kernel<<<dim3(N_ROWS * DDIM / 1024), 256, 0, stream>>>(
        src, (unsigned int*)src2q, N_ROWS * DDIM / 4);
    quant_i8_kernel<<<dim3(M_ANCH * DDIM / 1024), 256, 0, stream>>>(
        anc, (unsigned int*)anc2q, M_ANCH * DDIM / 4);
    anchor_norm_kernel<<<dim3(M_ANCH / 4), 256, 0, stream>>>(anc, norm_a);

    // dist: approx seed keys -> margin threshold -> approx collect -> exact rescore
    gemm_i8<0><<<dim3(SEED / 128, N_ROWS / 128), 256, 0, stream>>>(
        src2q, anc2q, norm_a, nullptr, nullptr, nullptr, nullptr, 0, score, SEED);
    topk_scan_kernel<<<dim3(N_ROWS / 4), 256, 0, stream>>>(
        score, norm_a, thrbuf, cnt, cand_i, cand_n);
    gemm_i8<1><<<dim3((M_ANCH - SEED) / 128, N_ROWS / 128), 256, 0, stream>>>(
        src2q, anc2q + (size_t)SEED * DDIM, norm_a + SEED, thrbuf,
        cnt, cand_i, cand_n, SEED, nullptr, 0);
    rescore_kernel<<<dim3(N_ROWS / 4), 256, 0, stream>>>(
        src, anc, cnt, cand_i, cand_n, bufA);

    // sums/zeros live in dead dist-region: zero them only now
    zero_kernel<<<dim3(14), 256, 0, stream>>>(sums1, 3584);

    // Weight prep (overlays dead src2q region)
    wsplit_kernel<<<dim3(DDIM / 64, DDIM / 64), 256, 0, stream>>>(W_fus, Wt_fus1, DDIM, DDIM);
    wsplit_kernel<<<dim3(FDIM / 64, DDIM / 64), 256, 0, stream>>>(W_e1, Wt_e1, DDIM, FDIM);
    wsplit_kernel<<<dim3(DDIM / 64, FDIM / 64), 256, 0, stream>>>(W_e2, Wt_e2, FDIM, DDIM);
    wsplit_kernel<<<dim3(DDIM / 64, DDIM / 64), 256, 0, stream>>>(W_d, Wt_d, DDIM, DDIM);
    gemm_kernel<0><<<dim3(4, 4), 256, 0, stream>>>(
        W_dim, DDIM, nullptr, 0, W_fus + DDIM * DDIM, zeros512, W_comb2, DDIM);
    bcomb_kernel<<<dim3(2), 256, 0, stream>>>(b_dim, W_fus + DDIM * DDIM, b_fus, b_comb);
    wsplit_kernel<<<dim3(DDIM / 64, DDIM / 64), 256, 0, stream>>>(W_comb2, Wt_comb2, DDIM, DDIM);

    // comb = src @ Wf1 + b_comb + neigh @ W_comb2   -> out, then BN1 (+f16 copy)
    cast_f16_kernel<<<dim3(N_ROWS * DDIM / 1024), 256, 0, stream>>>(
        src, srcH, N_ROWS * DDIM / 4);
    gemm_f16a<0, 0, 0, DDIM><<<dim3(DDIM / 128, N_ROWS / 128), 256, 0, stream>>>(
        srcH, Wt_fus1, b_comb, nullptr, out, DDIM);
    cast_f16_kernel<<<dim3(N_ROWS * DDIM / 1024), 256, 0, stream>>>(
        bufA, aH, N_ROWS * DDIM / 4);
    gemm_f16a<1, 0, 0, DDIM><<<dim3(DDIM / 128, N_ROWS / 128), 256, 0, stream>>>(
        aH, Wt_comb2, nullptr, out, out, DDIM);
    bn_stats_kernel<<<dim3(DDIM / 64, 16), 256, 0, stream>>>(out, sums1);
    bn_apply_kernel<0><<<dim3(8192), 256, 0, stream>>>(out, out, combH, sums1, g1, bt1, invN);

    // encoder (unchunked): hH = f16(tanh(comb@We1+b1)); t = hH@We2 + b2 + comb
    gemm_f16a<0, 1, 1, DDIM><<<dim3(FDIM / 128, N_ROWS / 128), 256, 0, stream>>>(
        combH, Wt_e1, b_e1, nullptr, hH, FDIM);
    gemm_f16a<1, 0, 0, FDIM><<<dim3(DDIM / 128, N_ROWS / 128), 256, 0, stream>>>(
        hH, Wt_e2, b_e2, out, bufA, DDIM);
    bn_stats_kernel<<<dim3(DDIM / 64, 16), 256, 0, stream>>>(bufA, sums2);
    bn_apply_kernel<0><<<dim3(8192), 256, 0, stream>>>(bufA, bufA, aH, sums2, g2, bt2, invN);

    // decoder -> out, BN3 + tanh
    gemm_f16a<0, 0, 0, DDIM><<<dim3(DDIM / 128, N_ROWS / 128), 256, 0, stream>>>(
        aH, Wt_d, b_d, nullptr, out, DDIM);
    bn_stats_kernel<<<dim3(DDIM / 64, 16), 256, 0, stream>>>(out, sums3);
    bn_apply_kernel<1><<<dim3(8192), 256, 0, stream>>>(out, out, nullptr, sums3, g_d, bt_d, invN);
}